// Round 9
// baseline (741.636 us; speedup 1.0000x reference)
//
#include <hip/hip_runtime.h>
#include <hip/hip_bf16.h>

// NewellGRUModel: B=512, S=1024, F=16, H=64.  bf16 in/out (proven r2..r8).
//
// r8 post-mortem: partial-gate exchange via LDS (pbuf) put a conflicted
// write->barrier->read round-trip on the serial critical path (8.4M bank
// conflicts), and weights parked in AGPRs (VGPR_Count=80 < 120 floats).
// r9: K-split INSIDE the wave. Lane l of wave `half` owns output
// o = 32*half + (l>>1), k-range [32*(l&1), 32*(l&1)+32). The cross-lane gate
// reduction is __shfl_xor(v,1) -- a quad-perm DPP (~5cyc VALU), NOT an LDS
// trip. The per-step s_barrier remains only for the h exchange (each wave
// publishes its 32 outputs to the shared hs[]). h-part uses float2
// accumulators over k-pairs (v_pk_fma_f32 candidate). Both lanes of a pair
// compute the nonlinearity redundantly; even lane writes hs[o].
// x staged per 16-step tile in LDS (r2/r8-proven), read 8 ch/lane by k-half.

template<bool BF16>
struct IO {
    static __device__ __forceinline__ float ld(const void* p, int i) {
        if constexpr (BF16) {
            unsigned short u = ((const unsigned short*)p)[i];
            union { unsigned int ui; float f; } c; c.ui = (unsigned int)u << 16;
            return c.f;
        } else {
            return ((const float*)p)[i];
        }
    }
    static __device__ __forceinline__ void st(void* p, int i, float v) {
        if constexpr (BF16) ((__hip_bfloat16*)p)[i] = __float2bfloat16(v);
        else ((float*)p)[i] = v;
    }
};

// Load 2 consecutive x elements (i even) as fp32 pair.
template<bool BF16>
__device__ __forceinline__ float2 ldx2(const void* p, int i) {
    if constexpr (BF16) {
        unsigned int u = *(const unsigned int*)((const unsigned short*)p + i);
        union { unsigned int ui; float f; } a, b;
        a.ui = u << 16; b.ui = u & 0xffff0000u;
        return make_float2(a.f, b.f);
    } else {
        return *(const float2*)((const float*)p + i);
    }
}

// mode: 0 = buffers are bf16, 1 = buffers are fp32.
__global__ void detect_dtype_kernel(const void* rkbuf, int* flag) {
    const float* f = (const float*)rkbuf;
    int ok = 0;
    for (int i = 0; i < 64; ++i) {
        float a = fabsf(f[i]);
        ok += (a > 1e-5f && a < 2.0f) ? 1 : 0;
    }
    *flag = (ok >= 48) ? 1 : 0;
}

template<bool BF16>
__global__ __launch_bounds__(128, 1)
void gru_full_kernel(const void* __restrict__ inp, const void* __restrict__ gk,
                     const void* __restrict__ rk,  const void* __restrict__ gb,
                     const void* __restrict__ w1,  const void* __restrict__ b1v,
                     const void* __restrict__ gam, const void* __restrict__ bet,
                     const void* __restrict__ muv, const void* __restrict__ vav,
                     const void* __restrict__ w2,  const void* __restrict__ bb2,
                     const void* __restrict__ Tp,  const int* __restrict__ mode,
                     void* __restrict__ out)
{
    const int want = BF16 ? 0 : 1;
    if (*mode != want) return;   // uniform branch, whole block exits

    const int b     = blockIdx.x;
    const int tid   = threadIdx.x;      // 0..127
    const int l     = tid & 63;         // lane within wave
    const int half  = tid >> 6;         // wave id: outputs [32*half, 32*half+32)
    const int o     = 32 * half + (l >> 1);   // this lane's output unit
    const int kh    = l & 1;            // k-half within the pair
    const int kbase = 32 * kh;

    __shared__ __align__(16) float xs[2][16][16];  // x tile (fp32)
    __shared__ __align__(16) float hs[64];         // shared hidden state
    __shared__ __align__(16) float sred[64];       // epilogue exchange

    using io = IO<BF16>;

    // ---- recurrent weights: 32 k-rows for this lane's k-half, as pairs ----
    float2 wz2[16], wr2[16], wh2[16];
#pragma unroll
    for (int i = 0; i < 16; ++i) {
        const int r0 = kbase + 2*i;
        wz2[i] = make_float2(io::ld(rk, r0*192 + o),       io::ld(rk, (r0+1)*192 + o));
        wr2[i] = make_float2(io::ld(rk, r0*192 + 64 + o),  io::ld(rk, (r0+1)*192 + 64 + o));
        wh2[i] = make_float2(io::ld(rk, r0*192 + 128 + o), io::ld(rk, (r0+1)*192 + 128 + o));
    }
    // ---- x-proj weights: kh=0 -> ch 0..7, kh=1 -> ch 8..14 (+0 pad) ----
    float kz[8], kr[8], khw[8];
#pragma unroll
    for (int c = 0; c < 8; ++c) {
        const int ch = 8*kh + c;
        const bool v = (ch < 15);
        kz[c]  = v ? io::ld(gk, ch*192 + o)       : 0.0f;
        kr[c]  = v ? io::ld(gk, ch*192 + 64 + o)  : 0.0f;
        khw[c] = v ? io::ld(gk, ch*192 + 128 + o) : 0.0f;
    }
    // biases only in kh=0 lane's partials (added once after the pair-reduce)
    const float bz  = kh ? 0.0f : (io::ld(gb, o)      + io::ld(gb, 192 + o));
    const float br  = kh ? 0.0f : (io::ld(gb, 64 + o) + io::ld(gb, 192 + 64 + o));
    const float bah = kh ? 0.0f : io::ld(gb, 192 + 128 + o);   // b_r[h]
    const float bax = kh ? 0.0f : io::ld(gb, 128 + o);         // b_i[h]
    const float hsel = kh ? 1.0f : 0.0f;   // ch15 (dsum) lives in kh=1 lanes

    if (kh == 0) hs[o] = 0.0f;     // h0 = 0
    __syncthreads();

    const int xbase = b * 16384;   // elements
    float2 xreg = ldx2<BF16>(inp, xbase + 2*tid);   // tile 0 (2 elems/thread)

    float h = 0.0f, dsum = 0.0f;

#pragma unroll 1
    for (int t = 0; t < 64; ++t) {
        // stage tile t (128 threads x 2 elems = 256)
        {
            const int e = 2*tid;
            *(float2*)&xs[t & 1][e >> 4][e & 15] = xreg;
        }
        __syncthreads();
        if (t < 63) xreg = ldx2<BF16>(inp, xbase + (t + 1) * 256 + 2*tid);

#pragma unroll 1
        for (int s2 = 0; s2 < 16; ++s2) {
            // x row, this lane's 8 channels (2-addr broadcast reads)
            const float4* xr = (const float4*)&xs[t & 1][s2][8*kh];
            float4 xa = xr[0], xc = xr[1];

            // h, this lane's k-half: 8 ds_read_b128 (2-addr broadcast, free)
            const float4* hp = (const float4*)&hs[kbase];
            float4 p0 = hp[0], p1 = hp[1], p2 = hp[2], p3 = hp[3];
            float4 p4 = hp[4], p5 = hp[5], p6 = hp[6], p7 = hp[7];
            asm volatile("" ::: "memory");

            // ---- x part (scalar chains) ----
            float az = bz, ar = br, ax = bax;
            az = fmaf(xa.x, kz[0], az); ar = fmaf(xa.x, kr[0], ar); ax = fmaf(xa.x, khw[0], ax);
            az = fmaf(xa.y, kz[1], az); ar = fmaf(xa.y, kr[1], ar); ax = fmaf(xa.y, khw[1], ax);
            az = fmaf(xa.z, kz[2], az); ar = fmaf(xa.z, kr[2], ar); ax = fmaf(xa.z, khw[2], ax);
            az = fmaf(xa.w, kz[3], az); ar = fmaf(xa.w, kr[3], ar); ax = fmaf(xa.w, khw[3], ax);
            az = fmaf(xc.x, kz[4], az); ar = fmaf(xc.x, kr[4], ar); ax = fmaf(xc.x, khw[4], ax);
            az = fmaf(xc.y, kz[5], az); ar = fmaf(xc.y, kr[5], ar); ax = fmaf(xc.y, khw[5], ax);
            az = fmaf(xc.z, kz[6], az); ar = fmaf(xc.z, kr[6], ar); ax = fmaf(xc.z, khw[6], ax);
            az = fmaf(xc.w, kz[7], az); ar = fmaf(xc.w, kr[7], ar); ax = fmaf(xc.w, khw[7], ax);
            dsum = fmaf(hsel, xc.w, dsum);   // ch15 (kh=1 lanes only)

            // ---- h part: float2 accumulators over k-pairs (pk-fma bait) ----
            float2 az2 = make_float2(0.f, 0.f);
            float2 ar2 = make_float2(0.f, 0.f);
            float2 ah2 = make_float2(0.f, 0.f);
            {
                const float4 q[8] = {p0, p1, p2, p3, p4, p5, p6, p7};
#pragma unroll
                for (int i = 0; i < 8; ++i) {
                    const float4 p = q[i];
                    az2.x = fmaf(p.x, wz2[2*i].x,   az2.x);
                    az2.y = fmaf(p.y, wz2[2*i].y,   az2.y);
                    ar2.x = fmaf(p.x, wr2[2*i].x,   ar2.x);
                    ar2.y = fmaf(p.y, wr2[2*i].y,   ar2.y);
                    ah2.x = fmaf(p.x, wh2[2*i].x,   ah2.x);
                    ah2.y = fmaf(p.y, wh2[2*i].y,   ah2.y);
                    az2.x = fmaf(p.z, wz2[2*i+1].x, az2.x);
                    az2.y = fmaf(p.w, wz2[2*i+1].y, az2.y);
                    ar2.x = fmaf(p.z, wr2[2*i+1].x, ar2.x);
                    ar2.y = fmaf(p.w, wr2[2*i+1].y, ar2.y);
                    ah2.x = fmaf(p.z, wh2[2*i+1].x, ah2.x);
                    ah2.y = fmaf(p.w, wh2[2*i+1].y, ah2.y);
                }
            }
            float ah = bah + ah2.x + ah2.y;
            az += az2.x + az2.y;
            ar += ar2.x + ar2.y;

            // ---- pair reduce: xor-1 is quad-perm DPP (VALU, ~5cyc) ----
            az += __shfl_xor(az, 1, 64);
            ar += __shfl_xor(ar, 1, 64);
            ah += __shfl_xor(ah, 1, 64);
            ax += __shfl_xor(ax, 1, 64);

            const float z   = __builtin_amdgcn_rcpf(1.0f + __expf(-az));
            const float r   = __builtin_amdgcn_rcpf(1.0f + __expf(-ar));
            const float pre = fmaf(r, ah, ax);
            const float e2  = __expf(2.0f * pre);
            const float th  = 1.0f - 2.0f * __builtin_amdgcn_rcpf(e2 + 1.0f);
            h = fmaf(z, h - th, th);   // z*h + (1-z)*tanh  (both pair lanes)

            if (kh == 0) hs[o] = h;    // publish this wave's 32 outputs
            __syncthreads();           // the ONE barrier per step
        }
    }

    // ---- epilogue: delta effect + dense head ----
    const float dall = dsum + __shfl_xor(dsum, 1, 64);   // kh=1 lanes held it
    const float T0 = io::ld(Tp, 0);
    if (kh == 0) sred[o] = fmaf(T0 * (1.0f / 1024.0f), dall, h);
    __syncthreads();

    if (half == 1) {   // one wave does the head
        const int j = l;   // 0..63
        float acc = io::ld(b1v, j);
#pragma unroll
        for (int k = 0; k < 64; ++k)
            acc = fmaf(sred[k], io::ld(w1, k*64 + j), acc);
        acc = fmaxf(acc, 0.0f);                                  // ReLU
        const float inv = rsqrtf(io::ld(vav, j) + 0.001f);       // BN_EPS
        acc = fmaf((acc - io::ld(muv, j)) * inv, io::ld(gam, j), io::ld(bet, j));

        float v = acc * io::ld(w2, j);
#pragma unroll
        for (int off = 32; off > 0; off >>= 1)
            v += __shfl_down(v, off);
        if (j == 0) io::st(out, b, v + io::ld(bb2, 0));
    }
}

extern "C" void kernel_launch(void* const* d_in, const int* in_sizes, int n_in,
                              void* d_out, int out_size, void* d_ws, size_t ws_size,
                              hipStream_t stream)
{
    const void* inp = d_in[0];   // (512,1024,16)
    const void* gk  = d_in[1];   // (15,192)
    const void* rk  = d_in[2];   // (64,192)
    const void* gb  = d_in[3];   // (2,192)
    const void* w1  = d_in[4];   // (64,64)
    const void* b1v = d_in[5];   // (64,)
    const void* gam = d_in[6];
    const void* bet = d_in[7];
    const void* muv = d_in[8];
    const void* vav = d_in[9];
    const void* w2  = d_in[10];  // (64,1)
    const void* bb2 = d_in[11];  // (1,)
    const void* Tp  = d_in[12];  // (1,)

    int* flag = (int*)d_ws;
    detect_dtype_kernel<<<dim3(1), dim3(1), 0, stream>>>(rk, flag);
    gru_full_kernel<true ><<<dim3(512), dim3(128), 0, stream>>>(
        inp, gk, rk, gb, w1, b1v, gam, bet, muv, vav, w2, bb2, Tp, flag, d_out);
    gru_full_kernel<false><<<dim3(512), dim3(128), 0, stream>>>(
        inp, gk, rk, gb, w1, b1v, gam, bet, muv, vav, w2, bb2, Tp, flag, d_out);
}

// Round 10
// 733.187 us; speedup vs baseline: 1.0115x; 1.0115x over previous
//
#include <hip/hip_runtime.h>
#include <hip/hip_bf16.h>

// NewellGRUModel: B=512, S=1024, F=16, H=64.  bf16 in/out (proven r2..r9).
//
// SMOKING GUN (r8/r9): VGPR_Count=80 with 120 per-lane weight floats, and
// ~300 VALU inst/step measured vs ~110 written. LLVM rematerializes the
// weight loads INSIDE the step loop (global_load_ushort L1-hits + shifts,
// invisible in FETCH_SIZE) instead of keeping them register-resident.
// r10 = r9 structure unchanged + KEEP(x): asm volatile("" : "+v"(x)) applied
// to every weight after load. The value becomes opaque -> remat impossible ->
// allocator must keep ~180 VGPRs live (fits; we run 1 wave/SIMD anyway).
//
// Mapping (r9, proven): 512 blocks x 128 thr. Lane l of wave `half` owns
// output o = 32*half + (l>>1), k-range [32*(l&1), ...+32). Pair-reduce via
// __shfl_xor(v,1) (quad-perm DPP). One __syncthreads per step (h exchange).
// x staged per 16-step tile in LDS.

#define KEEP(x) asm volatile("" : "+v"(x))

template<bool BF16>
struct IO {
    static __device__ __forceinline__ float ld(const void* p, int i) {
        if constexpr (BF16) {
            unsigned short u = ((const unsigned short*)p)[i];
            union { unsigned int ui; float f; } c; c.ui = (unsigned int)u << 16;
            return c.f;
        } else {
            return ((const float*)p)[i];
        }
    }
    static __device__ __forceinline__ void st(void* p, int i, float v) {
        if constexpr (BF16) ((__hip_bfloat16*)p)[i] = __float2bfloat16(v);
        else ((float*)p)[i] = v;
    }
};

// Load 2 consecutive x elements (i even) as fp32 pair.
template<bool BF16>
__device__ __forceinline__ float2 ldx2(const void* p, int i) {
    if constexpr (BF16) {
        unsigned int u = *(const unsigned int*)((const unsigned short*)p + i);
        union { unsigned int ui; float f; } a, b;
        a.ui = u << 16; b.ui = u & 0xffff0000u;
        return make_float2(a.f, b.f);
    } else {
        return *(const float2*)((const float*)p + i);
    }
}

// mode: 0 = buffers are bf16, 1 = buffers are fp32.
__global__ void detect_dtype_kernel(const void* rkbuf, int* flag) {
    const float* f = (const float*)rkbuf;
    int ok = 0;
    for (int i = 0; i < 64; ++i) {
        float a = fabsf(f[i]);
        ok += (a > 1e-5f && a < 2.0f) ? 1 : 0;
    }
    *flag = (ok >= 48) ? 1 : 0;
}

template<bool BF16>
__global__ __launch_bounds__(128, 1)
void gru_full_kernel(const void* __restrict__ inp, const void* __restrict__ gk,
                     const void* __restrict__ rk,  const void* __restrict__ gb,
                     const void* __restrict__ w1,  const void* __restrict__ b1v,
                     const void* __restrict__ gam, const void* __restrict__ bet,
                     const void* __restrict__ muv, const void* __restrict__ vav,
                     const void* __restrict__ w2,  const void* __restrict__ bb2,
                     const void* __restrict__ Tp,  const int* __restrict__ mode,
                     void* __restrict__ out)
{
    const int want = BF16 ? 0 : 1;
    if (*mode != want) return;   // uniform branch, whole block exits

    const int b     = blockIdx.x;
    const int tid   = threadIdx.x;      // 0..127
    const int l     = tid & 63;         // lane within wave
    const int half  = tid >> 6;         // wave id: outputs [32*half, 32*half+32)
    const int o     = 32 * half + (l >> 1);   // this lane's output unit
    const int kh    = l & 1;            // k-half within the pair
    const int kbase = 32 * kh;

    __shared__ __align__(16) float xs[2][16][16];  // x tile (fp32)
    __shared__ __align__(16) float hs[64];         // shared hidden state
    __shared__ __align__(16) float sred[64];       // epilogue exchange

    using io = IO<BF16>;

    // ---- recurrent weights: 32 k-rows for this lane's k-half ----
    float wz[32], wr[32], wh[32];
#pragma unroll
    for (int i = 0; i < 32; ++i) {
        const int row = kbase + i;
        wz[i] = io::ld(rk, row*192 + o);
        wr[i] = io::ld(rk, row*192 + 64 + o);
        wh[i] = io::ld(rk, row*192 + 128 + o);
        KEEP(wz[i]); KEEP(wr[i]); KEEP(wh[i]);   // defeat remat: must stay live
    }
    // ---- x-proj weights: kh=0 -> ch 0..7, kh=1 -> ch 8..14 (+0 pad) ----
    float kz[8], kr[8], khw[8];
#pragma unroll
    for (int c = 0; c < 8; ++c) {
        const int ch = 8*kh + c;
        const bool v = (ch < 15);
        kz[c]  = v ? io::ld(gk, ch*192 + o)       : 0.0f;
        kr[c]  = v ? io::ld(gk, ch*192 + 64 + o)  : 0.0f;
        khw[c] = v ? io::ld(gk, ch*192 + 128 + o) : 0.0f;
        KEEP(kz[c]); KEEP(kr[c]); KEEP(khw[c]);
    }
    // biases only in kh=0 lane's partials (added once before the pair-reduce)
    float bz  = kh ? 0.0f : (io::ld(gb, o)      + io::ld(gb, 192 + o));
    float br  = kh ? 0.0f : (io::ld(gb, 64 + o) + io::ld(gb, 192 + 64 + o));
    float bah = kh ? 0.0f : io::ld(gb, 192 + 128 + o);   // b_r[h]
    float bax = kh ? 0.0f : io::ld(gb, 128 + o);         // b_i[h]
    KEEP(bz); KEEP(br); KEEP(bah); KEEP(bax);
    const float hsel = kh ? 1.0f : 0.0f;   // ch15 (dsum) lives in kh=1 lanes

    if (kh == 0) hs[o] = 0.0f;     // h0 = 0
    __syncthreads();

    const int xbase = b * 16384;   // elements
    float2 xreg = ldx2<BF16>(inp, xbase + 2*tid);   // tile 0 (2 elems/thread)

    float h = 0.0f, dsum = 0.0f;

#pragma unroll 1
    for (int t = 0; t < 64; ++t) {
        // stage tile t (128 threads x 2 elems = 256)
        {
            const int e = 2*tid;
            *(float2*)&xs[t & 1][e >> 4][e & 15] = xreg;
        }
        __syncthreads();
        if (t < 63) xreg = ldx2<BF16>(inp, xbase + (t + 1) * 256 + 2*tid);

#pragma unroll 1
        for (int s2 = 0; s2 < 16; ++s2) {
            // x row, this lane's 8 channels (2-addr broadcast reads)
            const float4* xr = (const float4*)&xs[t & 1][s2][8*kh];
            float4 xa = xr[0], xc = xr[1];

            // h, this lane's k-half: 8 ds_read_b128 (2-addr broadcast)
            const float4* hp = (const float4*)&hs[kbase];
            float4 p0 = hp[0], p1 = hp[1], p2 = hp[2], p3 = hp[3];
            float4 p4 = hp[4], p5 = hp[5], p6 = hp[6], p7 = hp[7];
            asm volatile("" ::: "memory");

            // ---- x part ----
            float az = bz, ar = br, ax = bax;
            az = fmaf(xa.x, kz[0], az); ar = fmaf(xa.x, kr[0], ar); ax = fmaf(xa.x, khw[0], ax);
            az = fmaf(xa.y, kz[1], az); ar = fmaf(xa.y, kr[1], ar); ax = fmaf(xa.y, khw[1], ax);
            az = fmaf(xa.z, kz[2], az); ar = fmaf(xa.z, kr[2], ar); ax = fmaf(xa.z, khw[2], ax);
            az = fmaf(xa.w, kz[3], az); ar = fmaf(xa.w, kr[3], ar); ax = fmaf(xa.w, khw[3], ax);
            az = fmaf(xc.x, kz[4], az); ar = fmaf(xc.x, kr[4], ar); ax = fmaf(xc.x, khw[4], ax);
            az = fmaf(xc.y, kz[5], az); ar = fmaf(xc.y, kr[5], ar); ax = fmaf(xc.y, khw[5], ax);
            az = fmaf(xc.z, kz[6], az); ar = fmaf(xc.z, kr[6], ar); ax = fmaf(xc.z, khw[6], ax);
            az = fmaf(xc.w, kz[7], az); ar = fmaf(xc.w, kr[7], ar); ax = fmaf(xc.w, khw[7], ax);
            dsum = fmaf(hsel, xc.w, dsum);   // ch15 (kh=1 lanes only)

            // ---- h part: 32 k-values, 2 chains per gate ----
            float az1 = 0.f, ar1 = 0.f, ah0 = 0.f, ah1 = 0.f;
            {
                const float4 q[8] = {p0, p1, p2, p3, p4, p5, p6, p7};
#pragma unroll
                for (int i = 0; i < 4; ++i) {
                    const float4 p = q[i];
                    az  = fmaf(p.x, wz[4*i+0], az);
                    ar  = fmaf(p.x, wr[4*i+0], ar);
                    ah0 = fmaf(p.x, wh[4*i+0], ah0);
                    az  = fmaf(p.y, wz[4*i+1], az);
                    ar  = fmaf(p.y, wr[4*i+1], ar);
                    ah0 = fmaf(p.y, wh[4*i+1], ah0);
                    az  = fmaf(p.z, wz[4*i+2], az);
                    ar  = fmaf(p.z, wr[4*i+2], ar);
                    ah0 = fmaf(p.z, wh[4*i+2], ah0);
                    az  = fmaf(p.w, wz[4*i+3], az);
                    ar  = fmaf(p.w, wr[4*i+3], ar);
                    ah0 = fmaf(p.w, wh[4*i+3], ah0);
                }
#pragma unroll
                for (int i = 4; i < 8; ++i) {
                    const float4 p = q[i];
                    az1 = fmaf(p.x, wz[4*i+0], az1);
                    ar1 = fmaf(p.x, wr[4*i+0], ar1);
                    ah1 = fmaf(p.x, wh[4*i+0], ah1);
                    az1 = fmaf(p.y, wz[4*i+1], az1);
                    ar1 = fmaf(p.y, wr[4*i+1], ar1);
                    ah1 = fmaf(p.y, wh[4*i+1], ah1);
                    az1 = fmaf(p.z, wz[4*i+2], az1);
                    ar1 = fmaf(p.z, wr[4*i+2], ar1);
                    ah1 = fmaf(p.z, wh[4*i+2], ah1);
                    az1 = fmaf(p.w, wz[4*i+3], az1);
                    ar1 = fmaf(p.w, wr[4*i+3], ar1);
                    ah1 = fmaf(p.w, wh[4*i+3], ah1);
                }
            }
            az += az1;
            ar += ar1;
            float ah = bah + ah0 + ah1;

            // ---- pair reduce: xor-1 quad-perm DPP ----
            az += __shfl_xor(az, 1, 64);
            ar += __shfl_xor(ar, 1, 64);
            ah += __shfl_xor(ah, 1, 64);
            ax += __shfl_xor(ax, 1, 64);

            const float z   = __builtin_amdgcn_rcpf(1.0f + __expf(-az));
            const float r   = __builtin_amdgcn_rcpf(1.0f + __expf(-ar));
            const float pre = fmaf(r, ah, ax);
            const float e2  = __expf(2.0f * pre);
            const float th  = 1.0f - 2.0f * __builtin_amdgcn_rcpf(e2 + 1.0f);
            h = fmaf(z, h - th, th);   // z*h + (1-z)*tanh  (both pair lanes)

            if (kh == 0) hs[o] = h;    // publish this wave's 32 outputs
            __syncthreads();           // the ONE barrier per step
        }
    }

    // ---- epilogue: delta effect + dense head ----
    const float dall = dsum + __shfl_xor(dsum, 1, 64);   // kh=1 lanes held it
    const float T0 = io::ld(Tp, 0);
    if (kh == 0) sred[o] = fmaf(T0 * (1.0f / 1024.0f), dall, h);
    __syncthreads();

    if (half == 1) {   // one wave does the head
        const int j = l;   // 0..63
        float acc = io::ld(b1v, j);
#pragma unroll
        for (int k = 0; k < 64; ++k)
            acc = fmaf(sred[k], io::ld(w1, k*64 + j), acc);
        acc = fmaxf(acc, 0.0f);                                  // ReLU
        const float inv = rsqrtf(io::ld(vav, j) + 0.001f);       // BN_EPS
        acc = fmaf((acc - io::ld(muv, j)) * inv, io::ld(gam, j), io::ld(bet, j));

        float v = acc * io::ld(w2, j);
#pragma unroll
        for (int off = 32; off > 0; off >>= 1)
            v += __shfl_down(v, off);
        if (j == 0) io::st(out, b, v + io::ld(bb2, 0));
    }
}

extern "C" void kernel_launch(void* const* d_in, const int* in_sizes, int n_in,
                              void* d_out, int out_size, void* d_ws, size_t ws_size,
                              hipStream_t stream)
{
    const void* inp = d_in[0];   // (512,1024,16)
    const void* gk  = d_in[1];   // (15,192)
    const void* rk  = d_in[2];   // (64,192)
    const void* gb  = d_in[3];   // (2,192)
    const void* w1  = d_in[4];   // (64,64)
    const void* b1v = d_in[5];   // (64,)
    const void* gam = d_in[6];
    const void* bet = d_in[7];
    const void* muv = d_in[8];
    const void* vav = d_in[9];
    const void* w2  = d_in[10];  // (64,1)
    const void* bb2 = d_in[11];  // (1,)
    const void* Tp  = d_in[12];  // (1,)

    int* flag = (int*)d_ws;
    detect_dtype_kernel<<<dim3(1), dim3(1), 0, stream>>>(rk, flag);
    gru_full_kernel<true ><<<dim3(512), dim3(128), 0, stream>>>(
        inp, gk, rk, gb, w1, b1v, gam, bet, muv, vav, w2, bb2, Tp, flag, d_out);
    gru_full_kernel<false><<<dim3(512), dim3(128), 0, stream>>>(
        inp, gk, rk, gb, w1, b1v, gam, bet, muv, vav, w2, bb2, Tp, flag, d_out);
}

// Round 11
// 585.147 us; speedup vs baseline: 1.2674x; 1.2530x over previous
//
#include <hip/hip_runtime.h>
#include <hip/hip_bf16.h>

// NewellGRUModel: B=512, S=1024, F=16, H=64.  bf16 in/out (proven r2..r10).
//
// r10 post-mortem: 1 wave/SIMD (Occ ~10%) leaves ~940 cyc/step of exposed
// latency; weights parked in AGPRs cost a v_accvgpr_read per use. Fix both:
// 4-way K-split inside the quad (256 thr/block, 4 waves): lane l of wave w
// owns output o = 16w + (l>>2), k-range [16*(l&3), +16). Per-lane weights
// 120 -> 60 floats (true VGPR residency under the 128 cap), and
// __launch_bounds__(256,2) + 2048 waves gives 2 waves/SIMD -- two blocks
// interleave every stall. Gate reduce = shfl_xor 1 + shfl_xor 2 (quad-perm
// DPP, pure VALU). h double-buffered by step parity (kills the r9/r10
// latent race); ONE barrier per step. x staged per 16-step tile in LDS.

#define KEEP(x) asm volatile("" : "+v"(x))

template<bool BF16>
struct IO {
    static __device__ __forceinline__ float ld(const void* p, int i) {
        if constexpr (BF16) {
            unsigned short u = ((const unsigned short*)p)[i];
            union { unsigned int ui; float f; } c; c.ui = (unsigned int)u << 16;
            return c.f;
        } else {
            return ((const float*)p)[i];
        }
    }
    static __device__ __forceinline__ void st(void* p, int i, float v) {
        if constexpr (BF16) ((__hip_bfloat16*)p)[i] = __float2bfloat16(v);
        else ((float*)p)[i] = v;
    }
};

// mode: 0 = buffers are bf16, 1 = buffers are fp32.
__global__ void detect_dtype_kernel(const void* rkbuf, int* flag) {
    const float* f = (const float*)rkbuf;
    int ok = 0;
    for (int i = 0; i < 64; ++i) {
        float a = fabsf(f[i]);
        ok += (a > 1e-5f && a < 2.0f) ? 1 : 0;
    }
    *flag = (ok >= 48) ? 1 : 0;
}

template<bool BF16>
__global__ __launch_bounds__(256, 2)
void gru_full_kernel(const void* __restrict__ inp, const void* __restrict__ gk,
                     const void* __restrict__ rk,  const void* __restrict__ gb,
                     const void* __restrict__ w1,  const void* __restrict__ b1v,
                     const void* __restrict__ gam, const void* __restrict__ bet,
                     const void* __restrict__ muv, const void* __restrict__ vav,
                     const void* __restrict__ w2,  const void* __restrict__ bb2,
                     const void* __restrict__ Tp,  const int* __restrict__ mode,
                     void* __restrict__ out)
{
    const int want = BF16 ? 0 : 1;
    if (*mode != want) return;   // uniform branch, whole block exits

    const int b     = blockIdx.x;
    const int tid   = threadIdx.x;        // 0..255
    const int w     = tid >> 6;           // wave 0..3
    const int l     = tid & 63;           // lane
    const int o     = 16 * w + (l >> 2);  // this lane's output unit
    const int kq    = l & 3;              // k-quarter within the quad
    const int kbase = 16 * kq;

    __shared__ __align__(16) float xs[2][16][16];  // x tile (fp32)
    __shared__ __align__(16) float hs[2][64];      // h, dbuf by step parity
    __shared__ __align__(16) float sred[64];       // epilogue exchange

    using io = IO<BF16>;

    // ---- recurrent weights: 16 k-rows for this lane's k-quarter ----
    float wz[16], wr[16], wh[16];
#pragma unroll
    for (int i = 0; i < 16; ++i) {
        const int row = kbase + i;
        wz[i] = io::ld(rk, row*192 + o);
        wr[i] = io::ld(rk, row*192 + 64 + o);
        wh[i] = io::ld(rk, row*192 + 128 + o);
        KEEP(wz[i]); KEEP(wr[i]); KEEP(wh[i]);
    }
    // ---- x-proj weights: 4 channels per k-quarter (ch15 weight = 0 pad) ----
    float kz[4], kr[4], khw[4];
#pragma unroll
    for (int c = 0; c < 4; ++c) {
        const int ch = 4*kq + c;
        const bool v = (ch < 15);
        kz[c]  = v ? io::ld(gk, ch*192 + o)       : 0.0f;
        kr[c]  = v ? io::ld(gk, ch*192 + 64 + o)  : 0.0f;
        khw[c] = v ? io::ld(gk, ch*192 + 128 + o) : 0.0f;
        KEEP(kz[c]); KEEP(kr[c]); KEEP(khw[c]);
    }
    // biases only in kq=0 lane's partials (summed once in the quad-reduce)
    float bz  = kq ? 0.0f : (io::ld(gb, o)      + io::ld(gb, 192 + o));
    float br  = kq ? 0.0f : (io::ld(gb, 64 + o) + io::ld(gb, 192 + 64 + o));
    float bah = kq ? 0.0f : io::ld(gb, 192 + 128 + o);   // b_r[h]
    float bax = kq ? 0.0f : io::ld(gb, 128 + o);         // b_i[h]
    const float hsel = (kq == 3) ? 1.0f : 0.0f;          // ch15 -> dsum

    if (tid < 64) hs[0][tid] = 0.0f;   // h0 = 0
    __syncthreads();

    const int xbase = b * 16384;       // elements
    float xreg = io::ld(inp, xbase + tid);   // tile 0: 1 elem/thread

    float h = 0.0f, dsum = 0.0f;

#pragma unroll 1
    for (int t = 0; t < 64; ++t) {
        xs[t & 1][tid >> 4][tid & 15] = xreg;
        __syncthreads();               // staging visible (1 extra / 16 steps)
        if (t < 63) xreg = io::ld(inp, xbase + (t + 1) * 256 + tid);

#pragma unroll 1
        for (int s2 = 0; s2 < 16; ++s2) {
            const int s = t * 16 + s2;

            // x row, this lane's 4 channels; h, this lane's 16 k-values
            const float4 xv = *(const float4*)&xs[t & 1][s2][4*kq];
            const float4* hp = (const float4*)&hs[s & 1][kbase];
            float4 p0 = hp[0], p1 = hp[1], p2 = hp[2], p3 = hp[3];
            asm volatile("" ::: "memory");

            // ---- x part (12 FMA) ----
            float az = bz, ar = br, ax = bax;
            az = fmaf(xv.x, kz[0], az); ar = fmaf(xv.x, kr[0], ar); ax = fmaf(xv.x, khw[0], ax);
            az = fmaf(xv.y, kz[1], az); ar = fmaf(xv.y, kr[1], ar); ax = fmaf(xv.y, khw[1], ax);
            az = fmaf(xv.z, kz[2], az); ar = fmaf(xv.z, kr[2], ar); ax = fmaf(xv.z, khw[2], ax);
            az = fmaf(xv.w, kz[3], az); ar = fmaf(xv.w, kr[3], ar); ax = fmaf(xv.w, khw[3], ax);
            dsum = fmaf(hsel, xv.w, dsum);   // ch15 (kq=3 lanes only)

            // ---- h part (48 FMA, 2 chains per gate) ----
            float az1 = 0.f, ar1 = 0.f, ah0 = 0.f, ah1 = 0.f;
            {
                const float4 q[4] = {p0, p1, p2, p3};
#pragma unroll
                for (int i = 0; i < 2; ++i) {
                    const float4 p = q[i];
                    az  = fmaf(p.x, wz[4*i+0], az);
                    ar  = fmaf(p.x, wr[4*i+0], ar);
                    ah0 = fmaf(p.x, wh[4*i+0], ah0);
                    az  = fmaf(p.y, wz[4*i+1], az);
                    ar  = fmaf(p.y, wr[4*i+1], ar);
                    ah0 = fmaf(p.y, wh[4*i+1], ah0);
                    az  = fmaf(p.z, wz[4*i+2], az);
                    ar  = fmaf(p.z, wr[4*i+2], ar);
                    ah0 = fmaf(p.z, wh[4*i+2], ah0);
                    az  = fmaf(p.w, wz[4*i+3], az);
                    ar  = fmaf(p.w, wr[4*i+3], ar);
                    ah0 = fmaf(p.w, wh[4*i+3], ah0);
                }
#pragma unroll
                for (int i = 2; i < 4; ++i) {
                    const float4 p = q[i];
                    az1 = fmaf(p.x, wz[4*i+0], az1);
                    ar1 = fmaf(p.x, wr[4*i+0], ar1);
                    ah1 = fmaf(p.x, wh[4*i+0], ah1);
                    az1 = fmaf(p.y, wz[4*i+1], az1);
                    ar1 = fmaf(p.y, wr[4*i+1], ar1);
                    ah1 = fmaf(p.y, wh[4*i+1], ah1);
                    az1 = fmaf(p.z, wz[4*i+2], az1);
                    ar1 = fmaf(p.z, wr[4*i+2], ar1);
                    ah1 = fmaf(p.z, wh[4*i+2], ah1);
                    az1 = fmaf(p.w, wz[4*i+3], az1);
                    ar1 = fmaf(p.w, wr[4*i+3], ar1);
                    ah1 = fmaf(p.w, wh[4*i+3], ah1);
                }
            }
            az += az1;
            ar += ar1;
            float ah = bah + ah0 + ah1;

            // ---- quad reduce: xor-1 + xor-2, both quad-perm DPP ----
            az += __shfl_xor(az, 1, 64);  az += __shfl_xor(az, 2, 64);
            ar += __shfl_xor(ar, 1, 64);  ar += __shfl_xor(ar, 2, 64);
            ah += __shfl_xor(ah, 1, 64);  ah += __shfl_xor(ah, 2, 64);
            ax += __shfl_xor(ax, 1, 64);  ax += __shfl_xor(ax, 2, 64);

            const float z   = __builtin_amdgcn_rcpf(1.0f + __expf(-az));
            const float r   = __builtin_amdgcn_rcpf(1.0f + __expf(-ar));
            const float pre = fmaf(r, ah, ax);
            const float e2  = __expf(2.0f * pre);
            const float th  = 1.0f - 2.0f * __builtin_amdgcn_rcpf(e2 + 1.0f);
            h = fmaf(z, h - th, th);   // z*h + (1-z)*tanh (all quad lanes)

            if (kq == 0) hs[(s + 1) & 1][o] = h;   // publish to NEXT buffer
            __syncthreads();           // the ONE barrier per step
        }
    }

    // ---- epilogue: delta effect + dense head ----
    float dall = dsum;
    dall += __shfl_xor(dall, 1, 64);
    dall += __shfl_xor(dall, 2, 64);   // quad total (kq=3 lane held it)
    const float T0 = io::ld(Tp, 0);
    if (kq == 0) sred[o] = fmaf(T0 * (1.0f / 1024.0f), dall, h);
    __syncthreads();

    if (w == 0) {   // one wave does the head
        const int j = l;   // 0..63
        float acc = io::ld(b1v, j);
#pragma unroll
        for (int k = 0; k < 64; ++k)
            acc = fmaf(sred[k], io::ld(w1, k*64 + j), acc);
        acc = fmaxf(acc, 0.0f);                                  // ReLU
        const float inv = rsqrtf(io::ld(vav, j) + 0.001f);       // BN_EPS
        acc = fmaf((acc - io::ld(muv, j)) * inv, io::ld(gam, j), io::ld(bet, j));

        float v = acc * io::ld(w2, j);
#pragma unroll
        for (int off = 32; off > 0; off >>= 1)
            v += __shfl_down(v, off);
        if (j == 0) io::st(out, b, v + io::ld(bb2, 0));
    }
}

extern "C" void kernel_launch(void* const* d_in, const int* in_sizes, int n_in,
                              void* d_out, int out_size, void* d_ws, size_t ws_size,
                              hipStream_t stream)
{
    const void* inp = d_in[0];   // (512,1024,16)
    const void* gk  = d_in[1];   // (15,192)
    const void* rk  = d_in[2];   // (64,192)
    const void* gb  = d_in[3];   // (2,192)
    const void* w1  = d_in[4];   // (64,64)
    const void* b1v = d_in[5];   // (64,)
    const void* gam = d_in[6];
    const void* bet = d_in[7];
    const void* muv = d_in[8];
    const void* vav = d_in[9];
    const void* w2  = d_in[10];  // (64,1)
    const void* bb2 = d_in[11];  // (1,)
    const void* Tp  = d_in[12];  // (1,)

    int* flag = (int*)d_ws;
    detect_dtype_kernel<<<dim3(1), dim3(1), 0, stream>>>(rk, flag);
    gru_full_kernel<true ><<<dim3(512), dim3(256), 0, stream>>>(
        inp, gk, rk, gb, w1, b1v, gam, bet, muv, vav, w2, bb2, Tp, flag, d_out);
    gru_full_kernel<false><<<dim3(512), dim3(256), 0, stream>>>(
        inp, gk, rk, gb, w1, b1v, gam, bet, muv, vav, w2, bb2, Tp, flag, d_out);
}